// Round 11
// baseline (87.195 us; speedup 1.0000x reference)
//
#include <hip/hip_runtime.h>

// HNNPotential: u = f(d) via per-launch cubic-Hermite table (f64 build).
// Two kernels, NO cooperative launch:
//   K1 build_table: wave-per-node MLP eval (f64), zeroes the done-counter.
//   K2 pair_fin:    NxN pair sum per block; last block (device-scope
//                   atomic counter + threadfence) reduces partials,
//                   subtracts the diagonal f(EPS)*N exactly, writes out.
//
// ws layout: [0, 8200)         float2 nodes[1025] (f, h*f')
//            [16384, 20480)    double partials[512]
//            [20480, 20484)    unsigned done-counter

constexpr int N_ATOMS = 1024;
constexpr int H = 64;
constexpr int NB = 4;
constexpr float EPS = 0.01f;

constexpr int NT = 1024;                 // Hermite intervals
constexpr int NNODES = NT + 1;
constexpr float TMAX = 16.0f;
constexpr float INV_H = (float)NT / TMAX;          // 64.0 exactly
constexpr double DH = (double)TMAX / (double)NT;

constexpr int BLOCK = 256;
constexpr int NBLK = 512;                // 4 batches x 128 blocks
constexpr int JPW = 32;

// identical f32 code path everywhere (exact diagonal cancellation)
__device__ __forceinline__ float4 make_coef(float2 n0, float2 n1) {
    float dp = n1.x - n0.x;
    float c2 = fmaf(3.0f, dp, -fmaf(2.0f, n0.y, n1.y));   // 3D - 2m0 - m1
    float c3 = fmaf(-2.0f, dp, n0.y + n1.y);              // -2D + m0 + m1
    return make_float4(n0.x, n0.y, c2, c3);
}
__device__ __forceinline__ float heval(float4 c, float fr) {
    return fmaf(fr, fmaf(fr, fmaf(fr, c.w, c.z), c.y), c.x);
}

// ---- K1: one wave per node; lanes split the hidden dim (f64) ----
__global__ __launch_bounds__(BLOCK) void build_table(
    const float* __restrict__ W1, const float* __restrict__ b1,
    const float* __restrict__ W2, const float* __restrict__ b2,
    const float* __restrict__ W3, const float* __restrict__ b3,
    float2* __restrict__ nodes, unsigned* __restrict__ done)
{
    const int tid  = (int)threadIdx.x;
    const int lane = tid & 63;
    const int w    = tid >> 6;
    const int gw   = (int)blockIdx.x * (BLOCK / 64) + w;

    if (blockIdx.x == 0 && tid == 0) *done = 0u;   // reset ws-poisoned counter

    if (gw >= NNODES) return;
    const double d = (double)gw * DH;

    double a1 = d * (double)W1[lane] + (double)b1[lane];
    double s1 = 1.0 / (1.0 + exp(-a1));
    double h1 = a1 * s1;
    double g1 = (s1 + a1 * s1 * (1.0 - s1)) * (double)W1[lane];

    double acc = (double)b2[lane], dacc = 0.0;
    for (int k = 0; k < H; ++k) {
        double hk = __shfl(h1, k);
        double gk = __shfl(g1, k);
        double wt = (double)W2[k * H + lane];
        acc  += hk * wt;
        dacc += gk * wt;
    }
    double s2  = 1.0 / (1.0 + exp(-acc));
    double h2  = acc * s2;
    double dh2 = (s2 + acc * s2 * (1.0 - s2)) * dacc;

    double pu = h2  * (double)W3[lane];
    double du = dh2 * (double)W3[lane];
    for (int off = 32; off; off >>= 1) {
        pu += __shfl_down(pu, off);
        du += __shfl_down(du, off);
    }
    if (lane == 0)
        nodes[gw] = make_float2((float)((double)b3[0] + pu), (float)(du * DH));
}

// ---- K2: NxN pair sum; last finishing block reduces + finalizes ----
__global__ __launch_bounds__(BLOCK) void pair_fin(
    const float* __restrict__ pos, const float2* __restrict__ nodes,
    double* __restrict__ partials, unsigned* __restrict__ done,
    float* __restrict__ out)
{
    __shared__ float4 posl4[N_ATOMS * 3 / 4];   // 12 KB
    __shared__ float4 coef[NT];                 // 16 KB
    __shared__ float wred[BLOCK / 64];
    __shared__ bool  amLast;

    const int tid   = (int)threadIdx.x;
    const int bid   = (int)blockIdx.x;
    const int lane  = tid & 63;
    const int w     = tid >> 6;
    const int b     = bid >> 7;                 // batch
    const int r     = bid & 127;
    const int ibase = (r >> 3) * 64;
    const int jbase = (r & 7) * 128;

    const float4* p4 = (const float4*)(pos + (size_t)b * N_ATOMS * 3);
#pragma unroll
    for (int rr = 0; rr < 3; ++rr)
        posl4[tid + BLOCK * rr] = p4[tid + BLOCK * rr];
#pragma unroll
    for (int rr = 0; rr < NT / BLOCK; ++rr) {
        int k = tid + BLOCK * rr;
        coef[k] = make_coef(nodes[k], nodes[k + 1]);
    }
    __syncthreads();

    const float* posf = (const float*)posl4;
    const int i = ibase + lane;
    const float xi = posf[3 * i], yi = posf[3 * i + 1], zi = posf[3 * i + 2];

    float acc = 0.0f;
    const int j0 = jbase + w * JPW;
#pragma unroll
    for (int s = 0; s < JPW; ++s) {
        const int j = j0 + s;
        float dx = xi - posf[3 * j];
        float dy = yi - posf[3 * j + 1];
        float dz = zi - posf[3 * j + 2];
        float d  = sqrtf(fmaf(dx, dx, fmaf(dy, dy, fmaf(dz, dz, EPS * EPS))));
        float t  = d * INV_H;
        int   k  = min((int)t, NT - 1);
        float fr = t - (float)k;
        acc += heval(coef[k], fr);
    }

    for (int off = 32; off; off >>= 1) acc += __shfl_down(acc, off);
    if (lane == 0) wred[w] = acc;
    __syncthreads();

    if (tid == 0) {
        partials[bid] = (double)((wred[0] + wred[1]) + (wred[2] + wred[3]));
        __threadfence();                         // publish partial (device scope)
        unsigned prev = atomicAdd(done, 1u);     // device-scope by default
        amLast = (prev == (unsigned)(NBLK - 1));
    }
    __syncthreads();

    if (amLast) {
        __threadfence();                         // acquire all partials
        const volatile double* vp = (const volatile double*)partials;
        double s = vp[w * 128 + lane] + vp[w * 128 + 64 + lane];
        for (int off = 32; off; off >>= 1) s += __shfl_down(s, off);
        if (lane == 0) {
            // diagonal term via the identical f32 path (cancels exactly)
            float dd = sqrtf(fmaf(0.0f, 0.0f, fmaf(0.0f, 0.0f,
                             fmaf(0.0f, 0.0f, EPS * EPS))));
            float t  = dd * INV_H;
            int   k  = min((int)t, NT - 1);
            float fr = t - (float)k;
            float fe = heval(make_coef(nodes[k], nodes[k + 1]), fr);
            out[w] = (float)((s - (double)N_ATOMS * (double)fe)
                             * (0.5 / (double)N_ATOMS));
        }
    }
}

extern "C" void kernel_launch(void* const* d_in, const int* in_sizes, int n_in,
                              void* d_out, int out_size, void* d_ws, size_t ws_size,
                              hipStream_t stream) {
    const float* pos = (const float*)d_in[0];
    const float* W1  = (const float*)d_in[1];
    const float* b1  = (const float*)d_in[2];
    const float* W2  = (const float*)d_in[3];
    const float* b2  = (const float*)d_in[4];
    const float* W3  = (const float*)d_in[5];
    const float* b3  = (const float*)d_in[6];

    float2*   nodes    = (float2*)d_ws;
    double*   partials = (double*)((char*)d_ws + 16384);
    unsigned* done     = (unsigned*)((char*)d_ws + 20480);
    float*    out      = (float*)d_out;

    hipLaunchKernelGGL(build_table, dim3((NNODES + 3) / 4), dim3(BLOCK), 0,
                       stream, W1, b1, W2, b2, W3, b3, nodes, done);
    hipLaunchKernelGGL(pair_fin, dim3(NBLK), dim3(BLOCK), 0, stream,
                       pos, nodes, partials, done, out);
}